// Round 4
// baseline (212.522 us; speedup 1.0000x reference)
//
#include <hip/hip_runtime.h>
#include <hip/hip_bf16.h>

#define N_NODES 100000
#define N_EDGES 1600000
#define NBUCK   391      // ceil(100000/256) buckets of 256 dst nodes
#define BSHIFT  8
#define BCAP    6144     // entries/bucket: mean 4096 + <=768 align pad + tail -> safe

typedef __bf16 bf16x8 __attribute__((ext_vector_type(8)));
typedef float  f32x4  __attribute__((ext_vector_type(4)));
typedef float  f32x2  __attribute__((ext_vector_type(2)));

// Established facts:
//  - edge_index int32, float inputs fp32, OUTPUT fp32 (rounds 3-6).
//  - R6 865 -> R7 757 (CSR) -> R8 578 (hier scan) -> R9 447 (MFMA+bf16 halves)
//    -> R10 324 (bucketed build) -> R11 290 (8B gathers) -> R12 273 (fp8 halves)
//    -> R13 237 (8 nodes/wave agg1) -> R14 221 (aligned int4 csr, 8-deep MLP)
//    -> R15 212 (csr||gemm1 fused, agg1+gemm2 fused, h in LDS).
//  - R16 changes (this source; R17 bench was an infra failure, resubmitted):
//    (a) 16B uint4 gathers (4 lanes/node agg1, 2 lanes/node agg2) halve
//    request count at same bytes; (b) csr index loads software-pipelined;
//    (c) 391 buckets of 256 nodes halve bucketcsr critical path; (d) ht
//    stride 72->76 kills the 8-way LDS conflict (152B == 6 dwords mod 32).

__device__ inline unsigned char enc_fp8(float v) {
    return (unsigned char)(__builtin_amdgcn_cvt_pk_fp8_f32(v, v, 0, 0) & 0xFF);
}

// ---------------------------------------------------------------------------
// partition: bucket edges by dst>>8 into bbuf, block-aggregated reservation.
__global__ __launch_bounds__(256) void partition_k(const int* __restrict__ ei,
                                                   int* __restrict__ gcur,
                                                   unsigned* __restrict__ bbuf) {
    __shared__ int hist[NBUCK];
    __shared__ int cur[NBUCK];
    int t = threadIdx.x;
    for (int i = t; i < NBUCK; i += 256) hist[i] = 0;
    __syncthreads();
    int base = blockIdx.x * 4096;                 // 391 blocks * 4096 >= E
    unsigned pk[16];
    int bk[16];
#pragma unroll
    for (int i = 0; i < 16; ++i) {
        int e = base + t + i * 256;               // coalesced
        if (e < N_EDGES) {
            int s = ei[e], d = ei[N_EDGES + e];
            int b = d >> BSHIFT;
            pk[i] = ((unsigned)(d & 255) << 17) | (unsigned)s;  // s < 2^17
            bk[i] = b;
            atomicAdd(&hist[b], 1);
        } else bk[i] = -1;
    }
    __syncthreads();
    for (int i = t; i < NBUCK; i += 256)
        cur[i] = atomicAdd(&gcur[i], hist[i]);    // reserve block's runs
    __syncthreads();
#pragma unroll
    for (int i = 0; i < 16; ++i) {
        if (bk[i] >= 0) {
            int pos = atomicAdd(&cur[bk[i]], 1);  // LDS cursor
            bbuf[(size_t)bk[i] * BCAP + pos] = pk[i];
        }
    }
}

// ---------------------------------------------------------------------------
// K2 fused: blocks 0..390 build bucket CSR (256 nodes each, 1 node/thread);
// blocks 391..1953 run GEMM1. Independent halves share one launch.
__global__ __launch_bounds__(256) void csr_gemm1_k(const unsigned* __restrict__ bbuf,
                                                   const int* __restrict__ gcur,
                                                   int* __restrict__ cnt,
                                                   int* __restrict__ offsets,
                                                   int* __restrict__ csr,
                                                   const float* __restrict__ x,
                                                   const float* __restrict__ W1l,
                                                   const float* __restrict__ W1r,
                                                   unsigned char* __restrict__ c1l,
                                                   __bf16* __restrict__ c1r) {
    __shared__ __align__(16) char smem[34816];
    int t = threadIdx.x;
    if (blockIdx.x < NBUCK) {
        // ---- bucketcsr path: 1 node per thread
        int* lcnt = (int*)smem;            // 256 ints
        int* lcur = (int*)(smem + 1024);   // 256 ints
        int* ssum = (int*)(smem + 2048);   // 256 ints
        int b = blockIdx.x;
        int m = gcur[b];                              // entries in this bucket
        const unsigned* src = bbuf + (size_t)b * BCAP;
        lcnt[t] = 0;
        __syncthreads();
        for (int i = t; i < m; i += 256) atomicAdd(&lcnt[src[i] >> 17], 1);
        __syncthreads();
        int a0 = lcnt[t];
        ssum[t] = (a0 + 3) & ~3;                      // 16B-align segment sizes
        __syncthreads();
        for (int off = 1; off < 256; off <<= 1) {
            int v = (t >= off) ? ssum[t - off] : 0;
            __syncthreads();
            ssum[t] += v;
            __syncthreads();
        }
        int ebase = (t == 0) ? 0 : ssum[t - 1];
        lcur[t] = ebase;
        int n = (b << BSHIFT) + t;
        if (n < N_NODES) {
            cnt[n] = a0;
            offsets[n] = b * BCAP + ebase;            // csr keeps per-bucket gaps
        }
        __syncthreads();
        for (int i = t; i < m; i += 256) {
            unsigned p = src[i];
            int pos = atomicAdd(&lcur[p >> 17], 1);
            csr[(size_t)b * BCAP + pos] = (int)(p & 0x1FFFF);
        }
    } else {
        // ---- GEMM1 path (MFMA 16x16x32 bf16): [c1l | c1r] = x @ [W1_l | W1_r]
        __bf16* Bt = (__bf16*)smem;        // B^T[n][k], stride 136 = 128+8 pad
        for (int idx = t; idx < 8192; idx += 256) {   // W is [128][64] each
            int k = idx >> 6, n = idx & 63;
            Bt[n * 136 + k]        = (__bf16)W1l[idx];
            Bt[(n + 64) * 136 + k] = (__bf16)W1r[idx];
        }
        __syncthreads();

        int lane = t & 63, wave = t >> 6;
        int bid = blockIdx.x - NBUCK;                  // 1563 gemm blocks
        int mbase = bid * 64 + wave * 16;
        int col  = lane & 15;
        int kgrp = (lane >> 4) << 3;                   // 0,8,16,24
        int mrow = mbase + col;
        int mclamp = mrow < N_NODES ? mrow : N_NODES - 1;
        const float* arow = x + (size_t)mclamp * 128;

        f32x4 acc[8];
#pragma unroll
        for (int i = 0; i < 8; ++i) acc[i] = (f32x4){0.f, 0.f, 0.f, 0.f};

#pragma unroll
        for (int ks = 0; ks < 4; ++ks) {
            int kk = ks * 32 + kgrp;
            f32x4 a0 = *(const f32x4*)(arow + kk);
            f32x4 a1 = *(const f32x4*)(arow + kk + 4);
            bf16x8 a;
#pragma unroll
            for (int i = 0; i < 4; ++i) { a[i] = (__bf16)a0[i]; a[i + 4] = (__bf16)a1[i]; }
#pragma unroll
            for (int nt = 0; nt < 8; ++nt) {
                bf16x8 b = *(const bf16x8*)(Bt + (nt * 16 + col) * 136 + kk);
                acc[nt] = __builtin_amdgcn_mfma_f32_16x16x32_bf16(a, b, acc[nt], 0, 0, 0);
            }
        }

        // C/D: col = lane&15, row = (lane>>4)*4 + reg   [m89-verified]
        int r0 = mbase + ((lane >> 4) << 2);
#pragma unroll
        for (int r = 0; r < 4; ++r) {
            int m = r0 + r;
            if (m < N_NODES) {
#pragma unroll
                for (int nt = 0; nt < 4; ++nt)
                    c1l[(size_t)m * 64 + nt * 16 + col] = enc_fp8(acc[nt][r]);
#pragma unroll
                for (int nt = 4; nt < 8; ++nt)
                    c1r[(size_t)m * 64 + (nt - 4) * 16 + col] = (__bf16)acc[nt][r];
            }
        }
    }
}

// ---------------------------------------------------------------------------
// K3 fused: agg1 (mean-gather layer 1) + GEMM2 on the same 64-node tile.
// 4 lanes/node, uint4 16B gathers (half the requests of R15), pipelined
// csr index loads; h tile in LDS stride 76 (152B == 6 dwords mod 32 -> <=2-way).
__global__ __launch_bounds__(256) void agg1_gemm2_k(const unsigned char* __restrict__ c1l,
                                                    const __bf16* __restrict__ c1r,
                                                    const int* __restrict__ offsets,
                                                    const int* __restrict__ cnt,
                                                    const int* __restrict__ csr,
                                                    const float* __restrict__ b1,
                                                    const float* __restrict__ W2l,
                                                    const float* __restrict__ W2r,
                                                    unsigned char* __restrict__ c2l,
                                                    float* __restrict__ c2r) {
    __shared__ __bf16 Bt[64 * 72];   // W2^T, stride 72 = 64+8 pad
    __shared__ __bf16 ht[64 * 76];   // h tile, stride 76 (bank-conflict-free)
    int tid = threadIdx.x;
    for (int idx = tid; idx < 2048; idx += 256) {   // W2 is [64][32] each
        int k = idx >> 5, n = idx & 31;
        Bt[n * 72 + k]        = (__bf16)W2l[idx];
        Bt[(n + 32) * 72 + k] = (__bf16)W2r[idx];
    }

    int lane = tid & 63, wave = tid >> 6;
    // ---- agg1 phase: 16 nodes/wave, 4 lanes/node, 16 feats/lane, one pass
    int g = lane >> 2;                              // node group 0..15
    int nloc = wave * 16 + g;                       // 0..63 within tile
    int n = blockIdx.x * 64 + nloc;
    int f16b = (lane & 3) << 4;                     // feature base 0,16,32,48
    bool valid = n < N_NODES;
    int nc = valid ? n : N_NODES - 1;
    int beg = offsets[nc];
    int deg = valid ? cnt[n] : 0;
    int end = beg + deg;
    // root + bias issued before the gather chain
    bf16x8 rv0 = *(const bf16x8*)(c1r + (size_t)nc * 64 + f16b);
    bf16x8 rv1 = *(const bf16x8*)(c1r + (size_t)nc * 64 + f16b + 8);
    f32x4 b1v[4];
#pragma unroll
    for (int q = 0; q < 4; ++q) b1v[q] = *(const f32x4*)(b1 + f16b + q * 4);

    const int4* csr4 = (const int4*)csr;
    int4 j0 = csr4[beg >> 2];                       // pipelined index loads
    int4 j1 = csr4[(beg >> 2) + 1];
    float sum[16];
#pragma unroll
    for (int j = 0; j < 16; ++j) sum[j] = 0.f;
    for (int e = beg; e < end; e += 8) {
        int4 i0 = j0, i1 = j1;
        j0 = csr4[(e >> 2) + 2];                    // prefetch next iter (in-bounds:
        j1 = csr4[(e >> 2) + 3];                    //  <=32 entries of BCAP slack)
        int sidx[8] = {i0.x, i0.y, i0.z, i0.w, i1.x, i1.y, i1.z, i1.w};
        uint4 w[8];
#pragma unroll
        for (int u = 0; u < 8; ++u) {
            w[u] = (uint4){0u, 0u, 0u, 0u};         // fp8 0x00 decodes to 0.0f
            if (e + u < end)
                w[u] = *(const uint4*)(c1l + (size_t)sidx[u] * 64 + f16b);
        }
#pragma unroll
        for (int u = 0; u < 8; ++u) {
            f32x2 p0 = __builtin_amdgcn_cvt_pk_f32_fp8(w[u].x, 0);
            f32x2 p1 = __builtin_amdgcn_cvt_pk_f32_fp8(w[u].x, 1);
            f32x2 p2 = __builtin_amdgcn_cvt_pk_f32_fp8(w[u].y, 0);
            f32x2 p3 = __builtin_amdgcn_cvt_pk_f32_fp8(w[u].y, 1);
            f32x2 p4 = __builtin_amdgcn_cvt_pk_f32_fp8(w[u].z, 0);
            f32x2 p5 = __builtin_amdgcn_cvt_pk_f32_fp8(w[u].z, 1);
            f32x2 p6 = __builtin_amdgcn_cvt_pk_f32_fp8(w[u].w, 0);
            f32x2 p7 = __builtin_amdgcn_cvt_pk_f32_fp8(w[u].w, 1);
            sum[0]  += p0[0]; sum[1]  += p0[1]; sum[2]  += p1[0]; sum[3]  += p1[1];
            sum[4]  += p2[0]; sum[5]  += p2[1]; sum[6]  += p3[0]; sum[7]  += p3[1];
            sum[8]  += p4[0]; sum[9]  += p4[1]; sum[10] += p5[0]; sum[11] += p5[1];
            sum[12] += p6[0]; sum[13] += p6[1]; sum[14] += p7[0]; sum[15] += p7[1];
        }
    }
    float cf = deg > 0 ? (float)deg : 1.f;
    bf16x8 o0, o1;
#pragma unroll
    for (int j = 0; j < 16; ++j) {
        float rt = (j < 8) ? (float)rv0[j] : (float)rv1[j - 8];
        float v = valid ? (sum[j] / cf + rt + b1v[j >> 2][j & 3]) : 0.f;
        v = v > 0.f ? v : 0.f;
        if (j < 8) o0[j] = (__bf16)v; else o1[j - 8] = (__bf16)v;
    }
    *(bf16x8*)(ht + nloc * 76 + f16b)     = o0;
    *(bf16x8*)(ht + nloc * 76 + f16b + 8) = o1;
    __syncthreads();

    // ---- GEMM2 phase from LDS: [c2l | c2r] = ht @ [W2_l | W2_r]
    int col  = lane & 15;
    int kgrp = (lane >> 4) << 3;
    int mbase = blockIdx.x * 64 + wave * 16;
    const __bf16* arow = ht + (wave * 16 + col) * 76;

    f32x4 acc[4];
#pragma unroll
    for (int i = 0; i < 4; ++i) acc[i] = (f32x4){0.f, 0.f, 0.f, 0.f};

#pragma unroll
    for (int ks = 0; ks < 2; ++ks) {
        int kk = ks * 32 + kgrp;
        bf16x8 a = *(const bf16x8*)(arow + kk);
#pragma unroll
        for (int nt = 0; nt < 4; ++nt) {
            bf16x8 b = *(const bf16x8*)(Bt + (nt * 16 + col) * 72 + kk);
            acc[nt] = __builtin_amdgcn_mfma_f32_16x16x32_bf16(a, b, acc[nt], 0, 0, 0);
        }
    }

    int r0 = mbase + ((lane >> 4) << 2);
#pragma unroll
    for (int r = 0; r < 4; ++r) {
        int m = r0 + r;
        if (m < N_NODES) {
#pragma unroll
            for (int nt = 0; nt < 2; ++nt)
                c2l[(size_t)m * 32 + nt * 16 + col] = enc_fp8(acc[nt][r]);
#pragma unroll
            for (int nt = 2; nt < 4; ++nt)
                c2r[(size_t)m * 32 + (nt - 2) * 16 + col] = acc[nt][r];
        }
    }
}

// ---------------------------------------------------------------------------
// agg2 (fused final): 32 nodes/wave, 2 lanes/node, 16 feats/lane (16B gathers).
// Pipelined csr index loads; root c2r/Wh hoisted; head reduced with 1 shfl.
__global__ __launch_bounds__(256) void agg2_k(const unsigned char* __restrict__ c2l,
                                              const float* __restrict__ c2r,
                                              const int* __restrict__ offsets,
                                              const int* __restrict__ cnt,
                                              const int* __restrict__ csr,
                                              const float* __restrict__ b2,
                                              const float* __restrict__ Wh,
                                              const float* __restrict__ bh,
                                              float* __restrict__ out) {
    int wave = blockIdx.x * 4 + (threadIdx.x >> 6); // 782*4 waves, 32 nodes each
    int lane = threadIdx.x & 63;
    int g = lane >> 1;                              // node group 0..31
    int n = wave * 32 + g;                          // covers 100096, guarded
    int f16b = (lane & 1) << 4;                     // feature base 0 or 16
    bool valid = n < N_NODES;
    int nc = valid ? n : N_NODES - 1;
    int beg = offsets[nc], deg = valid ? cnt[n] : 0;
    int end = beg + deg;
    // hoist root + head weights + bias: issue before the gather chain
    f32x4 rr[4], wh[4], b2v[4];
#pragma unroll
    for (int q = 0; q < 4; ++q) {
        rr[q]  = *(const f32x4*)(c2r + (size_t)nc * 32 + f16b + q * 4);
        wh[q]  = *(const f32x4*)(Wh + f16b + q * 4);
        b2v[q] = *(const f32x4*)(b2 + f16b + q * 4);
    }
    const int4* csr4 = (const int4*)csr;
    int4 j0 = csr4[beg >> 2];
    int4 j1 = csr4[(beg >> 2) + 1];
    float sum[16];
#pragma unroll
    for (int j = 0; j < 16; ++j) sum[j] = 0.f;
    for (int e = beg; e < end; e += 8) {
        int4 i0 = j0, i1 = j1;
        j0 = csr4[(e >> 2) + 2];
        j1 = csr4[(e >> 2) + 3];
        int sidx[8] = {i0.x, i0.y, i0.z, i0.w, i1.x, i1.y, i1.z, i1.w};
        uint4 w[8];
#pragma unroll
        for (int u = 0; u < 8; ++u) {
            w[u] = (uint4){0u, 0u, 0u, 0u};
            if (e + u < end)
                w[u] = *(const uint4*)(c2l + (size_t)sidx[u] * 32 + f16b);
        }
#pragma unroll
        for (int u = 0; u < 8; ++u) {
            f32x2 p0 = __builtin_amdgcn_cvt_pk_f32_fp8(w[u].x, 0);
            f32x2 p1 = __builtin_amdgcn_cvt_pk_f32_fp8(w[u].x, 1);
            f32x2 p2 = __builtin_amdgcn_cvt_pk_f32_fp8(w[u].y, 0);
            f32x2 p3 = __builtin_amdgcn_cvt_pk_f32_fp8(w[u].y, 1);
            f32x2 p4 = __builtin_amdgcn_cvt_pk_f32_fp8(w[u].z, 0);
            f32x2 p5 = __builtin_amdgcn_cvt_pk_f32_fp8(w[u].z, 1);
            f32x2 p6 = __builtin_amdgcn_cvt_pk_f32_fp8(w[u].w, 0);
            f32x2 p7 = __builtin_amdgcn_cvt_pk_f32_fp8(w[u].w, 1);
            sum[0]  += p0[0]; sum[1]  += p0[1]; sum[2]  += p1[0]; sum[3]  += p1[1];
            sum[4]  += p2[0]; sum[5]  += p2[1]; sum[6]  += p3[0]; sum[7]  += p3[1];
            sum[8]  += p4[0]; sum[9]  += p4[1]; sum[10] += p5[0]; sum[11] += p5[1];
            sum[12] += p6[0]; sum[13] += p6[1]; sum[14] += p7[0]; sum[15] += p7[1];
        }
    }
    float cf = deg > 0 ? (float)deg : 1.f;
    float r = 0.f;
    f32x4 o[4];
#pragma unroll
    for (int j = 0; j < 16; ++j) {
        float v = sum[j] / cf + rr[j >> 2][j & 3] + b2v[j >> 2][j & 3];
        v = v > 0.f ? v : 0.f;
        o[j >> 2][j & 3] = v;
        r += v * wh[j >> 2][j & 3];
    }
    if (valid) {
#pragma unroll
        for (int q = 0; q < 4; ++q)
            *(f32x4*)(out + (size_t)n * 32 + f16b + q * 4) = o[q];
    }
    r += __shfl_xor(r, 1, 64);                      // reduce within pair
    if (valid && (lane & 1) == 0)
        out[(size_t)N_NODES * 32 + n] = r + bh[0];
}

// ---------------------------------------------------------------------------
extern "C" void kernel_launch(void* const* d_in, const int* in_sizes, int n_in,
                              void* d_out, int out_size, void* d_ws, size_t ws_size,
                              hipStream_t stream) {
    const float* x   = (const float*)d_in[0];
    const int*   ei  = (const int*)d_in[1];
    const float* W1l = (const float*)d_in[2];
    const float* b1  = (const float*)d_in[3];
    const float* W1r = (const float*)d_in[4];
    const float* W2l = (const float*)d_in[5];
    const float* b2  = (const float*)d_in[6];
    const float* W2r = (const float*)d_in[7];
    const float* Wh  = (const float*)d_in[8];
    const float* bh  = (const float*)d_in[9];
    float* out = (float*)d_out;

    // workspace layout (bytes):
    //   c1l  @ 0          N*64*1 =  6,400,000  (fp8, gathered)
    //   c1r  @ 6.4M       N*64*2 = 12,800,000  (bf16 root)
    //   (h region unused: h lives in LDS)
    //   c2l  @ 32.0M      N*32*1 =  3,200,000  (fp8, gathered)
    //   c2r  @ 35.2M      N*32*4 = 12,800,000  (fp32 root)
    //   cnt  @ 48.0M      N*4    =    400,000
    //   offs @ 48.4M      N*4    =    400,000
    //   gcur @ 48.8M      (pad 4096, zeroed)
    //   bbuf @ 48.804M    391*6144*4 = 9,609,216
    //   csr  @ 58.438M    391*6144*4 = 9,609,216
    char* ws = (char*)d_ws;
    unsigned char* c1l = (unsigned char*)(ws);
    __bf16*   c1r     = (__bf16*)(ws + 6400000);
    unsigned char* c2l = (unsigned char*)(ws + 32000000);
    float*    c2r     = (float*)(ws + 35200000);
    int*      cnt     = (int*)(ws + 48000000);
    int*      offsets = (int*)(ws + 48400000);
    int*      gcur    = (int*)(ws + 48800000);
    unsigned* bbuf    = (unsigned*)(ws + 48804096);
    int*      csr     = (int*)(ws + 58437888);

    hipMemsetAsync(gcur, 0, NBUCK * 4, stream);

    partition_k  <<<391, 256, 0, stream>>>(ei, gcur, bbuf);
    csr_gemm1_k  <<<NBUCK + 1563, 256, 0, stream>>>(bbuf, gcur, cnt, offsets, csr,
                                                    x, W1l, W1r, c1l, c1r);
    agg1_gemm2_k <<<1563, 256, 0, stream>>>(c1l, c1r, offsets, cnt, csr, b1,
                                            W2l, W2r, c2l, c2r);
    agg2_k       <<<782, 256, 0, stream>>>(c2l, c2r, offsets, cnt, csr, b2, Wh, bh, out);
}

// Round 5
// 204.020 us; speedup vs baseline: 1.0417x; 1.0417x over previous
//
#include <hip/hip_runtime.h>
#include <hip/hip_bf16.h>

#define N_NODES 100000
#define N_EDGES 1600000
#define NBUCK   391      // ceil(100000/256) buckets of 256 dst nodes
#define BSHIFT  8
#define BCAP    6144     // entries/bucket: mean 4096 + <=768 align pad + tail -> safe

typedef __bf16 bf16x8 __attribute__((ext_vector_type(8)));
typedef float  f32x4  __attribute__((ext_vector_type(4)));
typedef float  f32x2  __attribute__((ext_vector_type(2)));

// Established facts:
//  - edge_index int32, float inputs fp32, OUTPUT fp32 (rounds 3-6).
//  - R6 865 -> R7 757 (CSR) -> R8 578 (hier scan) -> R9 447 (MFMA+bf16 halves)
//    -> R10 324 (bucketed build) -> R11 290 (8B gathers) -> R12 273 (fp8 halves)
//    -> R13 237 (8 nodes/wave agg1) -> R14 221 (aligned int4 csr) -> R15 212
//    (csr||gemm1 fused, agg1+gemm2 fused, h in LDS) -> R16 212.5 (REGRESSION
//    in agg1_gemm2: 16B gathers doubled VGPR 56->104, occ 27->17.7%; offset
//    by 391-bucket csr + pipelined idx gains elsewhere).
//  - KEY LESSON (R16): 8 lanes/node x 8B already coalesces to ONE 64B line
//    per edge; wider per-lane loads buy nothing and cost occupancy. Gather
//    is latency-bound -> TLP (waves) is the hiding mechanism; keep VGPR low.
//  - R18: revert gather structure to 8 lanes/node uint2 (agg1) / 4 lanes/node
//    uint2 (agg2), sum[8]; KEEP 391-bucket csr, pipelined csr idx prefetch,
//    ht stride 76.

__device__ inline unsigned char enc_fp8(float v) {
    return (unsigned char)(__builtin_amdgcn_cvt_pk_fp8_f32(v, v, 0, 0) & 0xFF);
}

// ---------------------------------------------------------------------------
// partition: bucket edges by dst>>8 into bbuf, block-aggregated reservation.
__global__ __launch_bounds__(256) void partition_k(const int* __restrict__ ei,
                                                   int* __restrict__ gcur,
                                                   unsigned* __restrict__ bbuf) {
    __shared__ int hist[NBUCK];
    __shared__ int cur[NBUCK];
    int t = threadIdx.x;
    for (int i = t; i < NBUCK; i += 256) hist[i] = 0;
    __syncthreads();
    int base = blockIdx.x * 4096;                 // 391 blocks * 4096 >= E
    unsigned pk[16];
    int bk[16];
#pragma unroll
    for (int i = 0; i < 16; ++i) {
        int e = base + t + i * 256;               // coalesced
        if (e < N_EDGES) {
            int s = ei[e], d = ei[N_EDGES + e];
            int b = d >> BSHIFT;
            pk[i] = ((unsigned)(d & 255) << 17) | (unsigned)s;  // s < 2^17
            bk[i] = b;
            atomicAdd(&hist[b], 1);
        } else bk[i] = -1;
    }
    __syncthreads();
    for (int i = t; i < NBUCK; i += 256)
        cur[i] = atomicAdd(&gcur[i], hist[i]);    // reserve block's runs
    __syncthreads();
#pragma unroll
    for (int i = 0; i < 16; ++i) {
        if (bk[i] >= 0) {
            int pos = atomicAdd(&cur[bk[i]], 1);  // LDS cursor
            bbuf[(size_t)bk[i] * BCAP + pos] = pk[i];
        }
    }
}

// ---------------------------------------------------------------------------
// K2 fused: blocks 0..390 build bucket CSR (256 nodes each, 1 node/thread);
// blocks 391..1953 run GEMM1. Independent halves share one launch.
__global__ __launch_bounds__(256) void csr_gemm1_k(const unsigned* __restrict__ bbuf,
                                                   const int* __restrict__ gcur,
                                                   int* __restrict__ cnt,
                                                   int* __restrict__ offsets,
                                                   int* __restrict__ csr,
                                                   const float* __restrict__ x,
                                                   const float* __restrict__ W1l,
                                                   const float* __restrict__ W1r,
                                                   unsigned char* __restrict__ c1l,
                                                   __bf16* __restrict__ c1r) {
    __shared__ __align__(16) char smem[34816];
    int t = threadIdx.x;
    if (blockIdx.x < NBUCK) {
        // ---- bucketcsr path: 1 node per thread
        int* lcnt = (int*)smem;            // 256 ints
        int* lcur = (int*)(smem + 1024);   // 256 ints
        int* ssum = (int*)(smem + 2048);   // 256 ints
        int b = blockIdx.x;
        int m = gcur[b];                              // entries in this bucket
        const unsigned* src = bbuf + (size_t)b * BCAP;
        lcnt[t] = 0;
        __syncthreads();
        for (int i = t; i < m; i += 256) atomicAdd(&lcnt[src[i] >> 17], 1);
        __syncthreads();
        int a0 = lcnt[t];
        ssum[t] = (a0 + 3) & ~3;                      // 16B-align segment sizes
        __syncthreads();
        for (int off = 1; off < 256; off <<= 1) {
            int v = (t >= off) ? ssum[t - off] : 0;
            __syncthreads();
            ssum[t] += v;
            __syncthreads();
        }
        int ebase = (t == 0) ? 0 : ssum[t - 1];
        lcur[t] = ebase;
        int n = (b << BSHIFT) + t;
        if (n < N_NODES) {
            cnt[n] = a0;
            offsets[n] = b * BCAP + ebase;            // csr keeps per-bucket gaps
        }
        __syncthreads();
        for (int i = t; i < m; i += 256) {
            unsigned p = src[i];
            int pos = atomicAdd(&lcur[p >> 17], 1);
            csr[(size_t)b * BCAP + pos] = (int)(p & 0x1FFFF);
        }
    } else {
        // ---- GEMM1 path (MFMA 16x16x32 bf16): [c1l | c1r] = x @ [W1_l | W1_r]
        __bf16* Bt = (__bf16*)smem;        // B^T[n][k], stride 136 = 128+8 pad
        for (int idx = t; idx < 8192; idx += 256) {   // W is [128][64] each
            int k = idx >> 6, n = idx & 63;
            Bt[n * 136 + k]        = (__bf16)W1l[idx];
            Bt[(n + 64) * 136 + k] = (__bf16)W1r[idx];
        }
        __syncthreads();

        int lane = t & 63, wave = t >> 6;
        int bid = blockIdx.x - NBUCK;                  // 1563 gemm blocks
        int mbase = bid * 64 + wave * 16;
        int col  = lane & 15;
        int kgrp = (lane >> 4) << 3;                   // 0,8,16,24
        int mrow = mbase + col;
        int mclamp = mrow < N_NODES ? mrow : N_NODES - 1;
        const float* arow = x + (size_t)mclamp * 128;

        f32x4 acc[8];
#pragma unroll
        for (int i = 0; i < 8; ++i) acc[i] = (f32x4){0.f, 0.f, 0.f, 0.f};

#pragma unroll
        for (int ks = 0; ks < 4; ++ks) {
            int kk = ks * 32 + kgrp;
            f32x4 a0 = *(const f32x4*)(arow + kk);
            f32x4 a1 = *(const f32x4*)(arow + kk + 4);
            bf16x8 a;
#pragma unroll
            for (int i = 0; i < 4; ++i) { a[i] = (__bf16)a0[i]; a[i + 4] = (__bf16)a1[i]; }
#pragma unroll
            for (int nt = 0; nt < 8; ++nt) {
                bf16x8 b = *(const bf16x8*)(Bt + (nt * 16 + col) * 136 + kk);
                acc[nt] = __builtin_amdgcn_mfma_f32_16x16x32_bf16(a, b, acc[nt], 0, 0, 0);
            }
        }

        // C/D: col = lane&15, row = (lane>>4)*4 + reg   [m89-verified]
        int r0 = mbase + ((lane >> 4) << 2);
#pragma unroll
        for (int r = 0; r < 4; ++r) {
            int m = r0 + r;
            if (m < N_NODES) {
#pragma unroll
                for (int nt = 0; nt < 4; ++nt)
                    c1l[(size_t)m * 64 + nt * 16 + col] = enc_fp8(acc[nt][r]);
#pragma unroll
                for (int nt = 4; nt < 8; ++nt)
                    c1r[(size_t)m * 64 + (nt - 4) * 16 + col] = (__bf16)acc[nt][r];
            }
        }
    }
}

// ---------------------------------------------------------------------------
// K3 fused: agg1 (mean-gather layer 1) + GEMM2 on the same 64-node tile.
// R18: 8 lanes/node uint2 gathers (VGPR-lean, one 64B line/edge), sum[8],
// pipelined csr idx prefetch; h tile in LDS stride 76.
__global__ __launch_bounds__(256) void agg1_gemm2_k(const unsigned char* __restrict__ c1l,
                                                    const __bf16* __restrict__ c1r,
                                                    const int* __restrict__ offsets,
                                                    const int* __restrict__ cnt,
                                                    const int* __restrict__ csr,
                                                    const float* __restrict__ b1,
                                                    const float* __restrict__ W2l,
                                                    const float* __restrict__ W2r,
                                                    unsigned char* __restrict__ c2l,
                                                    float* __restrict__ c2r) {
    __shared__ __bf16 Bt[64 * 72];   // W2^T, stride 72 = 64+8 pad
    __shared__ __bf16 ht[64 * 76];   // h tile, stride 76
    int tid = threadIdx.x;
    for (int idx = tid; idx < 2048; idx += 256) {   // W2 is [64][32] each
        int k = idx >> 5, n = idx & 31;
        Bt[n * 72 + k]        = (__bf16)W2l[idx];
        Bt[(n + 32) * 72 + k] = (__bf16)W2r[idx];
    }

    int lane = tid & 63, wave = tid >> 6;
    // ---- agg1 phase: 8 nodes/wave, 8 lanes/node, 8 feats/lane; 2 passes = 64 nodes
    int g = lane >> 3;                              // node group 0..7
    int f8b = (lane & 7) << 3;                      // feature base 0..56
    f32x4 b1v0 = *(const f32x4*)(b1 + f8b);
    f32x4 b1v1 = *(const f32x4*)(b1 + f8b + 4);
    const int4* csr4 = (const int4*)csr;
#pragma unroll
    for (int p = 0; p < 2; ++p) {
        int lrow = p * 32 + wave * 8 + g;           // 0..63 within tile
        int n = blockIdx.x * 64 + lrow;
        bf16x8 o;
        if (n < N_NODES) {
            int beg = offsets[n], deg = cnt[n];     // beg % 4 == 0 (align pad)
            int end = beg + deg;
            bf16x8 rv = *(const bf16x8*)(c1r + (size_t)n * 64 + f8b);
            int4 j0 = csr4[beg >> 2];               // pipelined index loads
            int4 j1 = csr4[(beg >> 2) + 1];
            float sum[8];
#pragma unroll
            for (int j = 0; j < 8; ++j) sum[j] = 0.f;
            for (int e = beg; e < end; e += 8) {
                int4 i0 = j0, i1 = j1;
                j0 = csr4[(e >> 2) + 2];            // prefetch next iter (in-bounds:
                j1 = csr4[(e >> 2) + 3];            //  bucket slack >> 32 entries)
                int sidx[8] = {i0.x, i0.y, i0.z, i0.w, i1.x, i1.y, i1.z, i1.w};
                uint2 w[8];
#pragma unroll
                for (int u = 0; u < 8; ++u) {
                    w[u].x = 0u; w[u].y = 0u;       // fp8 0x00 decodes to 0.0f
                    if (e + u < end)
                        w[u] = *(const uint2*)(c1l + (size_t)sidx[u] * 64 + f8b);
                }
#pragma unroll
                for (int u = 0; u < 8; ++u) {
                    f32x2 p0 = __builtin_amdgcn_cvt_pk_f32_fp8(w[u].x, 0);
                    f32x2 p1 = __builtin_amdgcn_cvt_pk_f32_fp8(w[u].x, 1);
                    f32x2 p2 = __builtin_amdgcn_cvt_pk_f32_fp8(w[u].y, 0);
                    f32x2 p3 = __builtin_amdgcn_cvt_pk_f32_fp8(w[u].y, 1);
                    sum[0] += p0[0]; sum[1] += p0[1];
                    sum[2] += p1[0]; sum[3] += p1[1];
                    sum[4] += p2[0]; sum[5] += p2[1];
                    sum[6] += p3[0]; sum[7] += p3[1];
                }
            }
            float cf = deg > 0 ? (float)deg : 1.f;
#pragma unroll
            for (int j = 0; j < 8; ++j) {
                float v = sum[j] / cf + (float)rv[j] + ((j < 4) ? b1v0[j] : b1v1[j - 4]);
                o[j] = (__bf16)(v > 0.f ? v : 0.f);
            }
        } else {
#pragma unroll
            for (int j = 0; j < 8; ++j) o[j] = (__bf16)0.f;
        }
        *(bf16x8*)(ht + lrow * 76 + f8b) = o;
    }
    __syncthreads();

    // ---- GEMM2 phase from LDS: [c2l | c2r] = ht @ [W2_l | W2_r]
    int col  = lane & 15;
    int kgrp = (lane >> 4) << 3;
    int mbase = blockIdx.x * 64 + wave * 16;
    const __bf16* arow = ht + (wave * 16 + col) * 76;

    f32x4 acc[4];
#pragma unroll
    for (int i = 0; i < 4; ++i) acc[i] = (f32x4){0.f, 0.f, 0.f, 0.f};

#pragma unroll
    for (int ks = 0; ks < 2; ++ks) {
        int kk = ks * 32 + kgrp;
        bf16x8 a = *(const bf16x8*)(arow + kk);
#pragma unroll
        for (int nt = 0; nt < 4; ++nt) {
            bf16x8 b = *(const bf16x8*)(Bt + (nt * 16 + col) * 72 + kk);
            acc[nt] = __builtin_amdgcn_mfma_f32_16x16x32_bf16(a, b, acc[nt], 0, 0, 0);
        }
    }

    int r0 = mbase + ((lane >> 4) << 2);
#pragma unroll
    for (int r = 0; r < 4; ++r) {
        int m = r0 + r;
        if (m < N_NODES) {
#pragma unroll
            for (int nt = 0; nt < 2; ++nt)
                c2l[(size_t)m * 32 + nt * 16 + col] = enc_fp8(acc[nt][r]);
#pragma unroll
            for (int nt = 2; nt < 4; ++nt)
                c2r[(size_t)m * 32 + (nt - 2) * 16 + col] = acc[nt][r];
        }
    }
}

// ---------------------------------------------------------------------------
// agg2 (fused final): 16 nodes/wave, 4 lanes/node, 8 feats/lane (uint2 gathers).
// Pipelined csr idx prefetch; root c2r/Wh hoisted; head reduced with 2 shfls.
__global__ __launch_bounds__(256) void agg2_k(const unsigned char* __restrict__ c2l,
                                              const float* __restrict__ c2r,
                                              const int* __restrict__ offsets,
                                              const int* __restrict__ cnt,
                                              const int* __restrict__ csr,
                                              const float* __restrict__ b2,
                                              const float* __restrict__ Wh,
                                              const float* __restrict__ bh,
                                              float* __restrict__ out) {
    int wave = blockIdx.x * 4 + (threadIdx.x >> 6); // 1563*4 waves, 16 nodes each
    int lane = threadIdx.x & 63;
    int g = lane >> 2;                              // node group 0..15
    int n = wave * 16 + g;                          // covers 100032, guarded
    int f8b = (lane & 3) << 3;                      // feature base 0,8,16,24
    bool valid = n < N_NODES;
    int nc = valid ? n : N_NODES - 1;
    int beg = offsets[nc], deg = valid ? cnt[n] : 0;
    int end = beg + deg;
    // hoist root + head weights: issue before the gather chain
    f32x4 rr0 = *(const f32x4*)(c2r + (size_t)nc * 32 + f8b);
    f32x4 rr1 = *(const f32x4*)(c2r + (size_t)nc * 32 + f8b + 4);
    f32x4 wh0 = *(const f32x4*)(Wh + f8b);
    f32x4 wh1 = *(const f32x4*)(Wh + f8b + 4);
    const int4* csr4 = (const int4*)csr;
    int4 j0 = csr4[beg >> 2];
    int4 j1 = csr4[(beg >> 2) + 1];
    float sum[8];
#pragma unroll
    for (int j = 0; j < 8; ++j) sum[j] = 0.f;
    for (int e = beg; e < end; e += 8) {
        int4 i0 = j0, i1 = j1;
        j0 = csr4[(e >> 2) + 2];
        j1 = csr4[(e >> 2) + 3];
        int sidx[8] = {i0.x, i0.y, i0.z, i0.w, i1.x, i1.y, i1.z, i1.w};
        uint2 w[8];
#pragma unroll
        for (int u = 0; u < 8; ++u) {
            w[u].x = 0u; w[u].y = 0u;
            if (e + u < end)
                w[u] = *(const uint2*)(c2l + (size_t)sidx[u] * 32 + f8b);
        }
#pragma unroll
        for (int u = 0; u < 8; ++u) {
            f32x2 p0 = __builtin_amdgcn_cvt_pk_f32_fp8(w[u].x, 0);
            f32x2 p1 = __builtin_amdgcn_cvt_pk_f32_fp8(w[u].x, 1);
            f32x2 p2 = __builtin_amdgcn_cvt_pk_f32_fp8(w[u].y, 0);
            f32x2 p3 = __builtin_amdgcn_cvt_pk_f32_fp8(w[u].y, 1);
            sum[0] += p0[0]; sum[1] += p0[1];
            sum[2] += p1[0]; sum[3] += p1[1];
            sum[4] += p2[0]; sum[5] += p2[1];
            sum[6] += p3[0]; sum[7] += p3[1];
        }
    }
    float cf = deg > 0 ? (float)deg : 1.f;
    float r = 0.f;
    f32x4 o0, o1;
#pragma unroll
    for (int j = 0; j < 8; ++j) {
        float root = (j < 4) ? rr0[j] : rr1[j - 4];
        float whj  = (j < 4) ? wh0[j] : wh1[j - 4];
        float v = sum[j] / cf + root + b2[f8b + j];
        v = v > 0.f ? v : 0.f;
        if (j < 4) o0[j] = v; else o1[j - 4] = v;
        r += v * whj;
    }
    if (valid) {
        *(f32x4*)(out + (size_t)n * 32 + f8b) = o0;
        *(f32x4*)(out + (size_t)n * 32 + f8b + 4) = o1;
    }
    r += __shfl_xor(r, 1, 64);                      // reduce within quad
    r += __shfl_xor(r, 2, 64);
    if (valid && (lane & 3) == 0)
        out[(size_t)N_NODES * 32 + n] = r + bh[0];
}

// ---------------------------------------------------------------------------
extern "C" void kernel_launch(void* const* d_in, const int* in_sizes, int n_in,
                              void* d_out, int out_size, void* d_ws, size_t ws_size,
                              hipStream_t stream) {
    const float* x   = (const float*)d_in[0];
    const int*   ei  = (const int*)d_in[1];
    const float* W1l = (const float*)d_in[2];
    const float* b1  = (const float*)d_in[3];
    const float* W1r = (const float*)d_in[4];
    const float* W2l = (const float*)d_in[5];
    const float* b2  = (const float*)d_in[6];
    const float* W2r = (const float*)d_in[7];
    const float* Wh  = (const float*)d_in[8];
    const float* bh  = (const float*)d_in[9];
    float* out = (float*)d_out;

    // workspace layout (bytes):
    //   c1l  @ 0          N*64*1 =  6,400,000  (fp8, gathered)
    //   c1r  @ 6.4M       N*64*2 = 12,800,000  (bf16 root)
    //   (h region unused: h lives in LDS)
    //   c2l  @ 32.0M      N*32*1 =  3,200,000  (fp8, gathered)
    //   c2r  @ 35.2M      N*32*4 = 12,800,000  (fp32 root)
    //   cnt  @ 48.0M      N*4    =    400,000
    //   offs @ 48.4M      N*4    =    400,000
    //   gcur @ 48.8M      (pad 4096, zeroed)
    //   bbuf @ 48.804M    391*6144*4 = 9,609,216
    //   csr  @ 58.438M    391*6144*4 = 9,609,216
    char* ws = (char*)d_ws;
    unsigned char* c1l = (unsigned char*)(ws);
    __bf16*   c1r     = (__bf16*)(ws + 6400000);
    unsigned char* c2l = (unsigned char*)(ws + 32000000);
    float*    c2r     = (float*)(ws + 35200000);
    int*      cnt     = (int*)(ws + 48000000);
    int*      offsets = (int*)(ws + 48400000);
    int*      gcur    = (int*)(ws + 48800000);
    unsigned* bbuf    = (unsigned*)(ws + 48804096);
    int*      csr     = (int*)(ws + 58437888);

    hipMemsetAsync(gcur, 0, NBUCK * 4, stream);

    partition_k  <<<391, 256, 0, stream>>>(ei, gcur, bbuf);
    csr_gemm1_k  <<<NBUCK + 1563, 256, 0, stream>>>(bbuf, gcur, cnt, offsets, csr,
                                                    x, W1l, W1r, c1l, c1r);
    agg1_gemm2_k <<<1563, 256, 0, stream>>>(c1l, c1r, offsets, cnt, csr, b1,
                                            W2l, W2r, c2l, c2r);
    agg2_k       <<<1563, 256, 0, stream>>>(c2l, c2r, offsets, cnt, csr, b2, Wh, bh, out);
}